// Round 1
// 147.265 us; speedup vs baseline: 1.0446x; 1.0446x over previous
//
#include <hip/hip_runtime.h>
#include <hip/hip_bf16.h>
#include <stdint.h>

#define T_TOK 8192
#define DIN   1024
#define DOUT  1024
#define NEXP  8
#define CAP   1024
#define LN_EPS 1e-5f

#define BM 128
#define BN 128
#define BK 32      // per sub-buffer; 2 sub-buffers per K-chunk, double-buffered

typedef __attribute__((ext_vector_type(8))) short short8;
typedef __attribute__((ext_vector_type(4))) float f32x4;

__device__ __forceinline__ unsigned short f2bf(float f) {
    union { float f; unsigned int u; } v; v.f = f;
    unsigned int u = v.u;
    unsigned int r = u + 0x7FFFu + ((u >> 16) & 1u);   // RNE
    return (unsigned short)(r >> 16);
}
__device__ __forceinline__ float bf2f(unsigned short h) {
    union { unsigned int u; float f; } v; v.u = ((unsigned int)h) << 16;
    return v.f;
}

__device__ __forceinline__ void gld16(void* l, const void* g) {
    __builtin_amdgcn_global_load_lds(
        (const __attribute__((address_space(1))) unsigned int*)(uintptr_t)g,
        (__attribute__((address_space(3))) unsigned int*)(uintptr_t)l,
        16, 0, 0);
}

// ---- prep: XCD-affine (e = blk&7 matches gemm/ln consumers' XCD) ----
// [0,2048): 4 X rows -> Xb bf16 per block (4x float4/thread).
// [2048,4096): one 64x64 W tile -> Wt^T bf16 per block (LDS fp32 transpose).
__global__ __launch_bounds__(256) void prep_kernel(
    const float* __restrict__ X, const float* __restrict__ W,
    unsigned short* __restrict__ Xb, unsigned short* __restrict__ Wt) {
    __shared__ float tile[64][65];
    int blk = blockIdx.x;
    int tid = threadIdx.x;
    if (blk < 2048) {
        int e  = blk & 7;
        int r0 = (blk >> 3) * 4;                     // 4 rows per block
        size_t base = ((size_t)(e * CAP + r0)) * 256 + tid;   // float4 index
#pragma unroll
        for (int q = 0; q < 4; q++) {
            size_t i = base + (size_t)q * 256;       // next row, same col slot
            float4 v = ((const float4*)X)[i];
            ushort4 o;
            o.x = f2bf(v.x); o.y = f2bf(v.y); o.z = f2bf(v.z); o.w = f2bf(v.w);
            ((ushort4*)Xb)[i] = o;
        }
    } else {
        int t  = blk - 2048;
        int e  = t & 7;
        int tl = t >> 3;                             // 0..255 tiles per expert
        int k0 = (tl >> 4) * 64;
        int n0 = (tl & 15) * 64;
        const float* Wp = W + (size_t)e * DIN * DOUT;
        unsigned short* Wtp = Wt + (size_t)e * DIN * DOUT;
        int rr = tid >> 4;                           // 0..15
        int cc = tid & 15;                           // 0..15
        // load 64x64 fp32 tile, 256B contiguous per 16-lane group
#pragma unroll
        for (int q = 0; q < 4; q++) {
            int k = rr + q * 16;
            float4 v = *(const float4*)(Wp + (size_t)(k0 + k) * DOUT + n0 + cc * 4);
            tile[k][cc * 4 + 0] = v.x;
            tile[k][cc * 4 + 1] = v.y;
            tile[k][cc * 4 + 2] = v.z;
            tile[k][cc * 4 + 3] = v.w;
        }
        __syncthreads();
        // transposed bf16 store, 128B contiguous per 16-lane group
#pragma unroll
        for (int q = 0; q < 4; q++) {
            int n = rr + q * 16;
            ushort4 o;
            o.x = f2bf(tile[cc * 4 + 0][n]);
            o.y = f2bf(tile[cc * 4 + 1][n]);
            o.z = f2bf(tile[cc * 4 + 2][n]);
            o.w = f2bf(tile[cc * 4 + 3][n]);
            *(ushort4*)(Wtp + (size_t)(n0 + n) * DIN + k0 + cc * 4) = o;
        }
    }
}

// ---- GEMM: h = relu(Xb*Wt^T + b) -> Hb bf16 + per-64col-chunk stats P ----
// 128x128 tile, 4 waves, 4x4 mfma 16x16x32. e = blk&7 (XCD affinity).
// 2-phase double-buffered prefetch (T3 minimum recipe): K-chunk = 64
// (2x BK=32 sub-buffers, proven stride-32 conflict-free layout), LDS
// 2x32KB = 64KB keeps 2 blocks/CU. STAGE of chunk k+1 issued BEFORE the
// ds_read+MFMA of chunk k, so the global_load_lds is in flight during 32
// MFMAs; one vmcnt(0)+barrier per chunk (16 barriers, same count as before,
// but the drain now only waits the un-hidden remainder).
__global__ __launch_bounds__(256, 2) void gemm6_kernel(
    const unsigned short* __restrict__ Xb,   // [T][K] bf16
    const unsigned short* __restrict__ Wt,   // [E][N][K] bf16
    const float* __restrict__ Bias,
    unsigned short* __restrict__ Hb,         // [T][DOUT] bf16
    float2* __restrict__ P)                  // [T][16] (sum,sumsq)
{
    __shared__ unsigned short As[2][2][BM * BK];   // 32 KB
    __shared__ unsigned short Bs[2][2][BN * BK];   // 32 KB

    int blk = blockIdx.x;                    // 0..511
    int e   = blk & 7;
    int mi  = blk >> 6;
    int m0  = mi * BM;
    int ni  = (blk >> 3) & 7;
    int n0  = ni * BN;

    int tid  = threadIdx.x;
    int wave = tid >> 6;
    int lane = tid & 63;
    int wm   = (wave >> 1) * 64;
    int wn   = (wave & 1) * 64;
    int lrow = lane & 15;
    int quad = lane >> 4;

    const unsigned short* Ag = Xb + (size_t)(e * CAP + m0) * DIN;
    const unsigned short* Bg = Wt + (size_t)e * DOUT * DIN + (size_t)n0 * DIN;

    int l0 = tid;
    int l1 = tid + 256;
    int ar0 = l0 >> 2, ac0 = (l0 & 3) * 8;
    int ar1 = l1 >> 2, ac1 = (l1 & 3) * 8;

    f32x4 acc[4][4];
#pragma unroll
    for (int i = 0; i < 4; i++)
#pragma unroll
        for (int j = 0; j < 4; j++)
            acc[i][j] = (f32x4)(0.0f);

#define STAGE(buf, kb)                                                        \
    {                                                                         \
        _Pragma("unroll")                                                     \
        for (int s = 0; s < 2; s++) {                                         \
            int k0 = (kb) + s * BK;                                           \
            gld16(&As[buf][s][l0 * 8], Ag + (size_t)ar0 * DIN + k0 + ac0);    \
            gld16(&As[buf][s][l1 * 8], Ag + (size_t)ar1 * DIN + k0 + ac1);    \
            gld16(&Bs[buf][s][l0 * 8], Bg + (size_t)ar0 * DIN + k0 + ac0);    \
            gld16(&Bs[buf][s][l1 * 8], Bg + (size_t)ar1 * DIN + k0 + ac1);    \
        }                                                                     \
    }

#define COMPUTE(buf)                                                          \
    {                                                                         \
        _Pragma("unroll")                                                     \
        for (int s = 0; s < 2; s++) {                                         \
            short8 af[4], bfr[4];                                             \
            _Pragma("unroll")                                                 \
            for (int i = 0; i < 4; i++)                                       \
                af[i] = *(const short8*)&As[buf][s][(wm + i * 16 + lrow) * BK + quad * 8]; \
            _Pragma("unroll")                                                 \
            for (int j = 0; j < 4; j++)                                       \
                bfr[j] = *(const short8*)&Bs[buf][s][(wn + j * 16 + lrow) * BK + quad * 8]; \
            _Pragma("unroll")                                                 \
            for (int i = 0; i < 4; i++)                                       \
                _Pragma("unroll")                                             \
                for (int j = 0; j < 4; j++)                                   \
                    acc[i][j] = __builtin_amdgcn_mfma_f32_16x16x32_bf16(af[i], bfr[j], acc[i][j], 0, 0, 0); \
        }                                                                     \
    }

    STAGE(0, 0);
    __syncthreads();
    // 16 chunks of 64 K. Loop 2x-unrolled so buffer indices are static.
    for (int kb = 64; kb < 960; kb += 128) {   // kb = 64,192,...,832
        STAGE(1, kb);
        COMPUTE(0);
        __syncthreads();
        STAGE(0, kb + 64);
        COMPUTE(1);
        __syncthreads();
    }
    STAGE(1, 960);
    COMPUTE(0);         // chunk 896
    __syncthreads();
    COMPUTE(1);         // chunk 960

#undef STAGE
#undef COMPUTE

    float bias[4];
#pragma unroll
    for (int j = 0; j < 4; j++)
        bias[j] = Bias[e * DOUT + n0 + wn + j * 16 + lrow];

    int tok0  = e * CAP + m0 + wm;
    int chunk = ni * 2 + (wave & 1);

#pragma unroll
    for (int i = 0; i < 4; i++) {
#pragma unroll
        for (int r = 0; r < 4; r++) {
            float s = 0.f, ss = 0.f;
#pragma unroll
            for (int j = 0; j < 4; j++) {
                float v = fmaxf(acc[i][j][r] + bias[j], 0.f);
                acc[i][j][r] = v;
                s += v;
                ss = fmaf(v, v, ss);
            }
#pragma unroll
            for (int m = 1; m <= 8; m <<= 1) {   // reduce over lrow (16 lanes)
                s  += __shfl_xor(s, m);
                ss += __shfl_xor(ss, m);
            }
            int grow = tok0 + i * 16 + quad * 4 + r;
            if (lrow == 0)
                P[(size_t)grow * 16 + chunk] = make_float2(s, ss);
#pragma unroll
            for (int j = 0; j < 4; j++) {
                int gcol = n0 + wn + j * 16 + lrow;
                Hb[(size_t)grow * DOUT + gcol] = f2bf(acc[i][j][r]);
            }
        }
    }
}

// ---- LN: XCD-affine, 2 rows per block (params loaded once) ----
__global__ __launch_bounds__(256) void ln2_kernel(
    const unsigned short* __restrict__ Hb,
    const float2* __restrict__ P,
    const float* __restrict__ G,
    const float* __restrict__ Bt,
    float* __restrict__ Out)
{
    int blk = blockIdx.x;            // 0..4095
    int e   = blk & 7;
    int r2  = (blk >> 3) * 2;
    int row0 = e * CAP + r2;
    int tid = threadIdx.x;
    __shared__ float sh[2][2];

    if (tid < 32) {
        int r = tid >> 4;            // which of the 2 rows
        float2 p = P[(size_t)(row0 + r) * 16 + (tid & 15)];
        float s = p.x, ss = p.y;
#pragma unroll
        for (int m = 1; m <= 8; m <<= 1) {   // stays inside 16-lane group
            s  += __shfl_xor(s, m);
            ss += __shfl_xor(ss, m);
        }
        if ((tid & 15) == 0) {
            float mu  = s * (1.0f / DOUT);
            float var = fmaxf(ss * (1.0f / DOUT) - mu * mu, 0.f);
            sh[r][0] = mu;
            sh[r][1] = rsqrtf(var + LN_EPS);
        }
    }
    __syncthreads();

    float4 g = ((const float4*)G)[e * 256 + tid];
    float4 b = ((const float4*)Bt)[e * 256 + tid];
#pragma unroll
    for (int r = 0; r < 2; r++) {
        float mu = sh[r][0], rs = sh[r][1];
        ushort4 hb = ((const ushort4*)Hb)[(size_t)(row0 + r) * 256 + tid];
        float4 y;
        y.x = (bf2f(hb.x) - mu) * rs * g.x + b.x;
        y.y = (bf2f(hb.y) - mu) * rs * g.y + b.y;
        y.z = (bf2f(hb.z) - mu) * rs * g.z + b.z;
        y.w = (bf2f(hb.w) - mu) * rs * g.w + b.w;
        ((float4*)Out)[(size_t)(row0 + r) * 256 + tid] = y;
    }
}

extern "C" void kernel_launch(void* const* d_in, const int* in_sizes, int n_in,
                              void* d_out, int out_size, void* d_ws, size_t ws_size,
                              hipStream_t stream) {
    const float* x  = (const float*)d_in[0];
    // d_in[1] = expert_frequency (int64) — equal loads, unused
    const float* W  = (const float*)d_in[2];
    const float* b  = (const float*)d_in[3];
    const float* g  = (const float*)d_in[4];
    const float* be = (const float*)d_in[5];
    float* out = (float*)d_out;

    const size_t WT_BYTES = (size_t)NEXP * DIN * DOUT * 2;   // 16 MB
    const size_t XB_BYTES = (size_t)T_TOK * DIN * 2;         // 16 MB
    const size_t P_BYTES  = (size_t)T_TOK * 16 * 8;          // 1 MB
    const size_t HB_BYTES = (size_t)T_TOK * DOUT * 2;        // 16 MB
    if (ws_size < WT_BYTES + XB_BYTES + P_BYTES + HB_BYTES) return;

    unsigned short* Wt = (unsigned short*)d_ws;
    unsigned short* Xb = (unsigned short*)((char*)d_ws + WT_BYTES);
    float2* P = (float2*)((char*)d_ws + WT_BYTES + XB_BYTES);
    unsigned short* Hb = (unsigned short*)((char*)d_ws + WT_BYTES + XB_BYTES + P_BYTES);

    dim3 tb(256);
    prep_kernel<<<dim3(4096), tb, 0, stream>>>(x, W, Xb, Wt);
    gemm6_kernel<<<dim3(512), tb, 0, stream>>>(Xb, Wt, b, Hb, P);
    ln2_kernel<<<dim3(4096), tb, 0, stream>>>(Hb, P, g, be, out);
}

// Round 2
// 146.476 us; speedup vs baseline: 1.0503x; 1.0054x over previous
//
#include <hip/hip_runtime.h>
#include <hip/hip_bf16.h>
#include <stdint.h>

#define T_TOK 8192
#define DIN   1024
#define DOUT  1024
#define NEXP  8
#define CAP   1024
#define LN_EPS 1e-5f

// GEMM tile geometry
#define BM 256
#define BN 128
#define BKT 64                     // K-tile
#define ABUF (BM * BKT)            // 16384 ushorts (32 KB)
#define BBUF (BN * BKT)            //  8192 ushorts (16 KB)
#define BUFSZ (ABUF + BBUF)        // 24576 ushorts (48 KB)

typedef __attribute__((ext_vector_type(8))) short short8;
typedef __attribute__((ext_vector_type(4))) float f32x4;

__device__ __forceinline__ unsigned short f2bf(float f) {
    union { float f; unsigned int u; } v; v.f = f;
    unsigned int u = v.u;
    unsigned int r = u + 0x7FFFu + ((u >> 16) & 1u);   // RNE
    return (unsigned short)(r >> 16);
}
__device__ __forceinline__ float bf2f(unsigned short h) {
    union { unsigned int u; float f; } v; v.u = ((unsigned int)h) << 16;
    return v.f;
}

__device__ __forceinline__ void gld16(void* l, const void* g) {
    __builtin_amdgcn_global_load_lds(
        (const __attribute__((address_space(1))) unsigned int*)(uintptr_t)g,
        (__attribute__((address_space(3))) unsigned int*)(uintptr_t)l,
        16, 0, 0);
}

// ---- prep: XCD-affine (e = blk&7 matches gemm/ln consumers' XCD) ----
__global__ __launch_bounds__(256) void prep_kernel(
    const float* __restrict__ X, const float* __restrict__ W,
    unsigned short* __restrict__ Xb, unsigned short* __restrict__ Wt) {
    __shared__ float tile[64][65];
    int blk = blockIdx.x;
    int tid = threadIdx.x;
    if (blk < 2048) {
        int e  = blk & 7;
        int r0 = (blk >> 3) * 4;
        size_t base = ((size_t)(e * CAP + r0)) * 256 + tid;
#pragma unroll
        for (int q = 0; q < 4; q++) {
            size_t i = base + (size_t)q * 256;
            float4 v = ((const float4*)X)[i];
            ushort4 o;
            o.x = f2bf(v.x); o.y = f2bf(v.y); o.z = f2bf(v.z); o.w = f2bf(v.w);
            ((ushort4*)Xb)[i] = o;
        }
    } else {
        int t  = blk - 2048;
        int e  = t & 7;
        int tl = t >> 3;
        int k0 = (tl >> 4) * 64;
        int n0 = (tl & 15) * 64;
        const float* Wp = W + (size_t)e * DIN * DOUT;
        unsigned short* Wtp = Wt + (size_t)e * DIN * DOUT;
        int rr = tid >> 4;
        int cc = tid & 15;
#pragma unroll
        for (int q = 0; q < 4; q++) {
            int k = rr + q * 16;
            float4 v = *(const float4*)(Wp + (size_t)(k0 + k) * DOUT + n0 + cc * 4);
            tile[k][cc * 4 + 0] = v.x;
            tile[k][cc * 4 + 1] = v.y;
            tile[k][cc * 4 + 2] = v.z;
            tile[k][cc * 4 + 3] = v.w;
        }
        __syncthreads();
#pragma unroll
        for (int q = 0; q < 4; q++) {
            int n = rr + q * 16;
            ushort4 o;
            o.x = f2bf(tile[cc * 4 + 0][n]);
            o.y = f2bf(tile[cc * 4 + 1][n]);
            o.z = f2bf(tile[cc * 4 + 2][n]);
            o.w = f2bf(tile[cc * 4 + 3][n]);
            *(ushort4*)(Wtp + (size_t)(n0 + n) * DIN + k0 + cc * 4) = o;
        }
    }
}

// ---- GEMM: 256x128 tile, 8 waves, triple-buffered counted-vmcnt phases ----
// Per K-tile (64): 2 phases x {8 ds_read_b128 ; 3 global_load_lds ; barrier ;
// setprio(1) 16 MFMA setprio(0) ; [vmcnt(6) phase B] ; barrier}.
// Tile p+2 staged during tile p; steady-state wait = vmcnt(6) (T4, never 0).
// LDS rows are 128B -> T2 XOR swizzle on 16B slots (slot ^= row&7), realized
// as linear LDS dest + pre-swizzled GLOBAL source + swizzled ds_read (rule 21).
__global__ __launch_bounds__(512, 2) void gemm7_kernel(
    const unsigned short* __restrict__ Xb,   // [T][K] bf16
    const unsigned short* __restrict__ Wt,   // [E][N][K] bf16
    const float* __restrict__ Bias,
    unsigned short* __restrict__ Hb,         // [T][DOUT] bf16
    float2* __restrict__ P)                  // [T][16] (sum,sumsq)
{
    __shared__ unsigned short lds[3 * BUFSZ];   // 144 KB

    int blk = blockIdx.x;                    // 0..255
    int e   = blk & 7;                       // XCD affinity
    int ni  = (blk >> 3) & 7;
    int mi  = blk >> 6;                      // 0..3
    int m0  = mi * BM;
    int n0  = ni * BN;

    int t    = threadIdx.x;                  // 0..511
    int wave = t >> 6;
    int lane = t & 63;
    int wm   = (wave >> 1) * 64;             // 4 M-waves
    int wn   = (wave & 1) * 64;              // 2 N-waves
    int lrow = lane & 15;
    int quad = lane >> 4;
    int l7   = lrow & 7;

    const unsigned short* Ag = Xb + (size_t)(e * CAP + m0) * DIN;
    const unsigned short* Bg = Wt + (size_t)e * DOUT * DIN + (size_t)n0 * DIN;

    // staging: thread t covers (row = c*64 + t>>3, 16B group = t&7),
    // source pre-swizzled so LDS slot s holds global group s^(row&7).
    int trow   = t >> 3;
    int kg_src = (t & 7) ^ (trow & 7);

    // ds_read swizzled offsets (ushort units); frag (row, s) at slot (s*4+quad)^l7
    int aoff0 = (wm + lrow) * BKT + ((quad) ^ l7) * 8;
    int aoff1 = (wm + lrow) * BKT + ((4 + quad) ^ l7) * 8;
    int boff0 = (wn + lrow) * BKT + ((quad) ^ l7) * 8;
    int boff1 = (wn + lrow) * BKT + ((4 + quad) ^ l7) * 8;

    f32x4 acc[4][4];
#pragma unroll
    for (int i = 0; i < 4; i++)
#pragma unroll
        for (int j = 0; j < 4; j++)
            acc[i][j] = (f32x4)(0.0f);

#define STAGE_H(bb, k0, h)                                                     \
    {                                                                          \
        unsigned short* Ab_ = &lds[(bb) * BUFSZ];                              \
        unsigned short* Bb_ = &lds[(bb) * BUFSZ + ABUF];                       \
        gld16(Ab_ + (((h) * 2 + 0) * 512 + t) * 8,                             \
              Ag + (size_t)(((h) * 2 + 0) * 64 + trow) * DIN + (k0) + kg_src * 8); \
        gld16(Ab_ + (((h) * 2 + 1) * 512 + t) * 8,                             \
              Ag + (size_t)(((h) * 2 + 1) * 64 + trow) * DIN + (k0) + kg_src * 8); \
        gld16(Bb_ + ((h) * 512 + t) * 8,                                       \
              Bg + (size_t)((h) * 64 + trow) * DIN + (k0) + kg_src * 8);       \
    }

#define LOADFRAGS(bb, ao, bo)                                                  \
    {                                                                          \
        const unsigned short* Ab_ = &lds[(bb) * BUFSZ];                        \
        const unsigned short* Bb_ = &lds[(bb) * BUFSZ + ABUF];                 \
        _Pragma("unroll")                                                      \
        for (int i = 0; i < 4; i++)                                            \
            af[i] = *(const short8*)&Ab_[(ao) + i * 16 * BKT];                 \
        _Pragma("unroll")                                                      \
        for (int j = 0; j < 4; j++)                                            \
            bf[j] = *(const short8*)&Bb_[(bo) + j * 16 * BKT];                 \
    }

#define MFMA16()                                                               \
    {                                                                          \
        __builtin_amdgcn_s_setprio(1);                                         \
        _Pragma("unroll")                                                      \
        for (int i = 0; i < 4; i++)                                            \
            _Pragma("unroll")                                                  \
            for (int j = 0; j < 4; j++)                                        \
                acc[i][j] = __builtin_amdgcn_mfma_f32_16x16x32_bf16(           \
                    af[i], bf[j], acc[i][j], 0, 0, 0);                         \
        __builtin_amdgcn_s_setprio(0);                                         \
    }

#define BAR() __builtin_amdgcn_s_barrier()
#define VMW(n) asm volatile("s_waitcnt vmcnt(" #n ")" ::: "memory")

    // prologue: stage tiles 0,1 (12 gld16/wave); wait tile0 (6 newer in flight)
    STAGE_H(0, 0, 0);
    STAGE_H(0, 0, 1);
    STAGE_H(1, BKT, 0);
    STAGE_H(1, BKT, 1);
    VMW(6);
    BAR();

    int cur = 0, nxt = 1, fut = 2;
    for (int p = 0; p < 14; ++p) {
        int k2 = (p + 2) * BKT;
        {   // phase s=0
            short8 af[4], bf[4];
            LOADFRAGS(cur, aoff0, boff0);
            STAGE_H(fut, k2, 0);
            BAR();
            MFMA16();
            BAR();
        }
        {   // phase s=1
            short8 af[4], bf[4];
            LOADFRAGS(cur, aoff1, boff1);
            STAGE_H(fut, k2, 1);
            BAR();
            MFMA16();
            VMW(6);            // drain tile p+1's 6; keep tile p+2's 6 in flight
            BAR();
        }
        int tmp = cur; cur = nxt; nxt = fut; fut = tmp;
    }
    // tile 14 (no staging; drain tile 15 at end)
    {
        short8 af[4], bf[4];
        LOADFRAGS(cur, aoff0, boff0);
        BAR(); MFMA16(); BAR();
    }
    {
        short8 af[4], bf[4];
        LOADFRAGS(cur, aoff1, boff1);
        BAR(); MFMA16();
        VMW(0);
        BAR();
    }
    // tile 15
    {
        short8 af[4], bf[4];
        LOADFRAGS(nxt, aoff0, boff0);
        BAR(); MFMA16(); BAR();
    }
    {
        short8 af[4], bf[4];
        LOADFRAGS(nxt, aoff1, boff1);
        BAR(); MFMA16();
    }

#undef STAGE_H
#undef LOADFRAGS
#undef MFMA16
#undef BAR
#undef VMW

    // fence: keep epilogue VMEM out of the counted-vmcnt loop region
    asm volatile("" ::: "memory");

    float bias[4];
#pragma unroll
    for (int j = 0; j < 4; j++)
        bias[j] = Bias[e * DOUT + n0 + wn + j * 16 + lrow];

    int tok0  = e * CAP + m0 + wm;
    int chunk = ni * 2 + (wave & 1);

#pragma unroll
    for (int i = 0; i < 4; i++) {
#pragma unroll
        for (int r = 0; r < 4; r++) {
            float s = 0.f, ss = 0.f;
#pragma unroll
            for (int j = 0; j < 4; j++) {
                float v = fmaxf(acc[i][j][r] + bias[j], 0.f);
                acc[i][j][r] = v;
                s += v;
                ss = fmaf(v, v, ss);
            }
#pragma unroll
            for (int m = 1; m <= 8; m <<= 1) {   // reduce over lrow (16 lanes)
                s  += __shfl_xor(s, m);
                ss += __shfl_xor(ss, m);
            }
            int grow = tok0 + i * 16 + quad * 4 + r;
            if (lrow == 0)
                P[(size_t)grow * 16 + chunk] = make_float2(s, ss);
#pragma unroll
            for (int j = 0; j < 4; j++) {
                int gcol = n0 + wn + j * 16 + lrow;
                Hb[(size_t)grow * DOUT + gcol] = f2bf(acc[i][j][r]);
            }
        }
    }
}

// ---- LN: XCD-affine, 2 rows per block (params loaded once) ----
__global__ __launch_bounds__(256) void ln2_kernel(
    const unsigned short* __restrict__ Hb,
    const float2* __restrict__ P,
    const float* __restrict__ G,
    const float* __restrict__ Bt,
    float* __restrict__ Out)
{
    int blk = blockIdx.x;            // 0..4095
    int e   = blk & 7;
    int r2  = (blk >> 3) * 2;
    int row0 = e * CAP + r2;
    int tid = threadIdx.x;
    __shared__ float sh[2][2];

    if (tid < 32) {
        int r = tid >> 4;
        float2 p = P[(size_t)(row0 + r) * 16 + (tid & 15)];
        float s = p.x, ss = p.y;
#pragma unroll
        for (int m = 1; m <= 8; m <<= 1) {
            s  += __shfl_xor(s, m);
            ss += __shfl_xor(ss, m);
        }
        if ((tid & 15) == 0) {
            float mu  = s * (1.0f / DOUT);
            float var = fmaxf(ss * (1.0f / DOUT) - mu * mu, 0.f);
            sh[r][0] = mu;
            sh[r][1] = rsqrtf(var + LN_EPS);
        }
    }
    __syncthreads();

    float4 g = ((const float4*)G)[e * 256 + tid];
    float4 b = ((const float4*)Bt)[e * 256 + tid];
#pragma unroll
    for (int r = 0; r < 2; r++) {
        float mu = sh[r][0], rs = sh[r][1];
        ushort4 hb = ((const ushort4*)Hb)[(size_t)(row0 + r) * 256 + tid];
        float4 y;
        y.x = (bf2f(hb.x) - mu) * rs * g.x + b.x;
        y.y = (bf2f(hb.y) - mu) * rs * g.y + b.y;
        y.z = (bf2f(hb.z) - mu) * rs * g.z + b.z;
        y.w = (bf2f(hb.w) - mu) * rs * g.w + b.w;
        ((float4*)Out)[(size_t)(row0 + r) * 256 + tid] = y;
    }
}

extern "C" void kernel_launch(void* const* d_in, const int* in_sizes, int n_in,
                              void* d_out, int out_size, void* d_ws, size_t ws_size,
                              hipStream_t stream) {
    const float* x  = (const float*)d_in[0];
    // d_in[1] = expert_frequency (int64) — equal loads, unused
    const float* W  = (const float*)d_in[2];
    const float* b  = (const float*)d_in[3];
    const float* g  = (const float*)d_in[4];
    const float* be = (const float*)d_in[5];
    float* out = (float*)d_out;

    const size_t WT_BYTES = (size_t)NEXP * DIN * DOUT * 2;   // 16 MB
    const size_t XB_BYTES = (size_t)T_TOK * DIN * 2;         // 16 MB
    const size_t P_BYTES  = (size_t)T_TOK * 16 * 8;          // 1 MB
    const size_t HB_BYTES = (size_t)T_TOK * DOUT * 2;        // 16 MB
    if (ws_size < WT_BYTES + XB_BYTES + P_BYTES + HB_BYTES) return;

    unsigned short* Wt = (unsigned short*)d_ws;
    unsigned short* Xb = (unsigned short*)((char*)d_ws + WT_BYTES);
    float2* P = (float2*)((char*)d_ws + WT_BYTES + XB_BYTES);
    unsigned short* Hb = (unsigned short*)((char*)d_ws + WT_BYTES + XB_BYTES + P_BYTES);

    prep_kernel<<<dim3(4096), dim3(256), 0, stream>>>(x, W, Xb, Wt);
    gemm7_kernel<<<dim3(256), dim3(512), 0, stream>>>(Xb, Wt, b, Hb, P);
    ln2_kernel<<<dim3(4096), dim3(256), 0, stream>>>(Hb, P, g, be, out);
}

// Round 3
// 142.118 us; speedup vs baseline: 1.0825x; 1.0307x over previous
//
#include <hip/hip_runtime.h>
#include <hip/hip_bf16.h>
#include <stdint.h>

#define T_TOK 8192
#define DIN   1024
#define DOUT  1024
#define NEXP  8
#define CAP   1024
#define LN_EPS 1e-5f

// GEMM tile geometry
#define BM 256
#define BN 128
#define BKT 64                     // K-tile
#define ABUF (BM * BKT)            // 16384 ushorts (32 KB)
#define BBUF (BN * BKT)            //  8192 ushorts (16 KB)
#define BUFSZ (ABUF + BBUF)        // 24576 ushorts (48 KB)

typedef __attribute__((ext_vector_type(8))) short short8;
typedef __attribute__((ext_vector_type(4))) float f32x4;

__device__ __forceinline__ unsigned short f2bf(float f) {
    union { float f; unsigned int u; } v; v.f = f;
    unsigned int u = v.u;
    unsigned int r = u + 0x7FFFu + ((u >> 16) & 1u);   // RNE
    return (unsigned short)(r >> 16);
}
__device__ __forceinline__ float bf2f(unsigned short h) {
    union { unsigned int u; float f; } v; v.u = ((unsigned int)h) << 16;
    return v.f;
}

__device__ __forceinline__ void gld16(void* l, const void* g) {
    __builtin_amdgcn_global_load_lds(
        (const __attribute__((address_space(1))) unsigned int*)(uintptr_t)g,
        (__attribute__((address_space(3))) unsigned int*)(uintptr_t)l,
        16, 0, 0);
}

// ---- prep: XCD-affine (e = blk&7 matches gemm/ln consumers' XCD) ----
// [0,1024): 8 X rows -> Xb bf16 per block.
// [1024,3072): one 64x64 W tile -> Wt^T bf16 per block (LDS fp32 transpose).
__global__ __launch_bounds__(256) void prep_kernel(
    const float* __restrict__ X, const float* __restrict__ W,
    unsigned short* __restrict__ Xb, unsigned short* __restrict__ Wt) {
    __shared__ float tile[64][65];
    int blk = blockIdx.x;
    int tid = threadIdx.x;
    if (blk < 1024) {
        int e  = blk & 7;
        int r0 = (blk >> 3) * 8;                     // 8 rows per block
        size_t base = ((size_t)(e * CAP + r0)) * 256 + tid;   // float4 index
#pragma unroll
        for (int q = 0; q < 8; q++) {
            size_t i = base + (size_t)q * 256;       // next row, same col slot
            float4 v = ((const float4*)X)[i];
            ushort4 o;
            o.x = f2bf(v.x); o.y = f2bf(v.y); o.z = f2bf(v.z); o.w = f2bf(v.w);
            ((ushort4*)Xb)[i] = o;
        }
    } else {
        int t  = blk - 1024;
        int e  = t & 7;
        int tl = t >> 3;                             // 0..255 tiles per expert
        int k0 = (tl >> 4) * 64;
        int n0 = (tl & 15) * 64;
        const float* Wp = W + (size_t)e * DIN * DOUT;
        unsigned short* Wtp = Wt + (size_t)e * DIN * DOUT;
        int rr = tid >> 4;                           // 0..15
        int cc = tid & 15;                           // 0..15
#pragma unroll
        for (int q = 0; q < 4; q++) {
            int k = rr + q * 16;
            float4 v = *(const float4*)(Wp + (size_t)(k0 + k) * DOUT + n0 + cc * 4);
            tile[k][cc * 4 + 0] = v.x;
            tile[k][cc * 4 + 1] = v.y;
            tile[k][cc * 4 + 2] = v.z;
            tile[k][cc * 4 + 3] = v.w;
        }
        __syncthreads();
#pragma unroll
        for (int q = 0; q < 4; q++) {
            int n = rr + q * 16;
            ushort4 o;
            o.x = f2bf(tile[cc * 4 + 0][n]);
            o.y = f2bf(tile[cc * 4 + 1][n]);
            o.z = f2bf(tile[cc * 4 + 2][n]);
            o.w = f2bf(tile[cc * 4 + 3][n]);
            *(ushort4*)(Wtp + (size_t)(n0 + n) * DIN + k0 + cc * 4) = o;
        }
    }
}

// ---- GEMM: 256x128 tile, 8 waves, triple-buffered counted-vmcnt phases ----
// (unchanged from R2 — measured at structural time; see session journal)
__global__ __launch_bounds__(512, 2) void gemm7_kernel(
    const unsigned short* __restrict__ Xb,   // [T][K] bf16
    const unsigned short* __restrict__ Wt,   // [E][N][K] bf16
    const float* __restrict__ Bias,
    unsigned short* __restrict__ Hb,         // [T][DOUT] bf16
    float2* __restrict__ P)                  // [T][16] (sum,sumsq)
{
    __shared__ unsigned short lds[3 * BUFSZ];   // 144 KB

    int blk = blockIdx.x;                    // 0..255
    int e   = blk & 7;                       // XCD affinity
    int ni  = (blk >> 3) & 7;
    int mi  = blk >> 6;                      // 0..3
    int m0  = mi * BM;
    int n0  = ni * BN;

    int t    = threadIdx.x;                  // 0..511
    int wave = t >> 6;
    int lane = t & 63;
    int wm   = (wave >> 1) * 64;             // 4 M-waves
    int wn   = (wave & 1) * 64;              // 2 N-waves
    int lrow = lane & 15;
    int quad = lane >> 4;
    int l7   = lrow & 7;

    const unsigned short* Ag = Xb + (size_t)(e * CAP + m0) * DIN;
    const unsigned short* Bg = Wt + (size_t)e * DOUT * DIN + (size_t)n0 * DIN;

    int trow   = t >> 3;
    int kg_src = (t & 7) ^ (trow & 7);

    int aoff0 = (wm + lrow) * BKT + ((quad) ^ l7) * 8;
    int aoff1 = (wm + lrow) * BKT + ((4 + quad) ^ l7) * 8;
    int boff0 = (wn + lrow) * BKT + ((quad) ^ l7) * 8;
    int boff1 = (wn + lrow) * BKT + ((4 + quad) ^ l7) * 8;

    f32x4 acc[4][4];
#pragma unroll
    for (int i = 0; i < 4; i++)
#pragma unroll
        for (int j = 0; j < 4; j++)
            acc[i][j] = (f32x4)(0.0f);

#define STAGE_H(bb, k0, h)                                                     \
    {                                                                          \
        unsigned short* Ab_ = &lds[(bb) * BUFSZ];                              \
        unsigned short* Bb_ = &lds[(bb) * BUFSZ + ABUF];                       \
        gld16(Ab_ + (((h) * 2 + 0) * 512 + t) * 8,                             \
              Ag + (size_t)(((h) * 2 + 0) * 64 + trow) * DIN + (k0) + kg_src * 8); \
        gld16(Ab_ + (((h) * 2 + 1) * 512 + t) * 8,                             \
              Ag + (size_t)(((h) * 2 + 1) * 64 + trow) * DIN + (k0) + kg_src * 8); \
        gld16(Bb_ + ((h) * 512 + t) * 8,                                       \
              Bg + (size_t)((h) * 64 + trow) * DIN + (k0) + kg_src * 8);       \
    }

#define LOADFRAGS(bb, ao, bo)                                                  \
    {                                                                          \
        const unsigned short* Ab_ = &lds[(bb) * BUFSZ];                        \
        const unsigned short* Bb_ = &lds[(bb) * BUFSZ + ABUF];                 \
        _Pragma("unroll")                                                      \
        for (int i = 0; i < 4; i++)                                            \
            af[i] = *(const short8*)&Ab_[(ao) + i * 16 * BKT];                 \
        _Pragma("unroll")                                                      \
        for (int j = 0; j < 4; j++)                                            \
            bf[j] = *(const short8*)&Bb_[(bo) + j * 16 * BKT];                 \
    }

#define MFMA16()                                                               \
    {                                                                          \
        __builtin_amdgcn_s_setprio(1);                                         \
        _Pragma("unroll")                                                      \
        for (int i = 0; i < 4; i++)                                            \
            _Pragma("unroll")                                                  \
            for (int j = 0; j < 4; j++)                                        \
                acc[i][j] = __builtin_amdgcn_mfma_f32_16x16x32_bf16(           \
                    af[i], bf[j], acc[i][j], 0, 0, 0);                         \
        __builtin_amdgcn_s_setprio(0);                                         \
    }

#define BAR() __builtin_amdgcn_s_barrier()
#define VMW(n) asm volatile("s_waitcnt vmcnt(" #n ")" ::: "memory")

    STAGE_H(0, 0, 0);
    STAGE_H(0, 0, 1);
    STAGE_H(1, BKT, 0);
    STAGE_H(1, BKT, 1);
    VMW(6);
    BAR();

    int cur = 0, nxt = 1, fut = 2;
    for (int p = 0; p < 14; ++p) {
        int k2 = (p + 2) * BKT;
        {   // phase s=0
            short8 af[4], bf[4];
            LOADFRAGS(cur, aoff0, boff0);
            STAGE_H(fut, k2, 0);
            BAR();
            MFMA16();
            BAR();
        }
        {   // phase s=1
            short8 af[4], bf[4];
            LOADFRAGS(cur, aoff1, boff1);
            STAGE_H(fut, k2, 1);
            BAR();
            MFMA16();
            VMW(6);            // drain tile p+1's 6; keep tile p+2's 6 in flight
            BAR();
        }
        int tmp = cur; cur = nxt; nxt = fut; fut = tmp;
    }
    {
        short8 af[4], bf[4];
        LOADFRAGS(cur, aoff0, boff0);
        BAR(); MFMA16(); BAR();
    }
    {
        short8 af[4], bf[4];
        LOADFRAGS(cur, aoff1, boff1);
        BAR(); MFMA16();
        VMW(0);
        BAR();
    }
    {
        short8 af[4], bf[4];
        LOADFRAGS(nxt, aoff0, boff0);
        BAR(); MFMA16(); BAR();
    }
    {
        short8 af[4], bf[4];
        LOADFRAGS(nxt, aoff1, boff1);
        BAR(); MFMA16();
    }

#undef STAGE_H
#undef LOADFRAGS
#undef MFMA16
#undef BAR
#undef VMW

    asm volatile("" ::: "memory");

    float bias[4];
#pragma unroll
    for (int j = 0; j < 4; j++)
        bias[j] = Bias[e * DOUT + n0 + wn + j * 16 + lrow];

    int tok0  = e * CAP + m0 + wm;
    int chunk = ni * 2 + (wave & 1);

#pragma unroll
    for (int i = 0; i < 4; i++) {
#pragma unroll
        for (int r = 0; r < 4; r++) {
            float s = 0.f, ss = 0.f;
#pragma unroll
            for (int j = 0; j < 4; j++) {
                float v = fmaxf(acc[i][j][r] + bias[j], 0.f);
                acc[i][j][r] = v;
                s += v;
                ss = fmaf(v, v, ss);
            }
#pragma unroll
            for (int m = 1; m <= 8; m <<= 1) {   // reduce over lrow (16 lanes)
                s  += __shfl_xor(s, m);
                ss += __shfl_xor(ss, m);
            }
            int grow = tok0 + i * 16 + quad * 4 + r;
            if (lrow == 0)
                P[(size_t)grow * 16 + chunk] = make_float2(s, ss);
#pragma unroll
            for (int j = 0; j < 4; j++) {
                int gcol = n0 + wn + j * 16 + lrow;
                Hb[(size_t)grow * DOUT + gcol] = f2bf(acc[i][j][r]);
            }
        }
    }
}

// ---- LN: XCD-affine, 8 rows per block (params loaded once per 8 rows) ----
__global__ __launch_bounds__(256) void ln2_kernel(
    const unsigned short* __restrict__ Hb,
    const float2* __restrict__ P,
    const float* __restrict__ G,
    const float* __restrict__ Bt,
    float* __restrict__ Out)
{
    int blk = blockIdx.x;            // 0..1023
    int e   = blk & 7;
    int r8  = (blk >> 3) * 8;
    int row0 = e * CAP + r8;
    int tid = threadIdx.x;
    __shared__ float sh[8][2];

    if (tid < 128) {
        int r = tid >> 4;            // which of the 8 rows
        float2 p = P[(size_t)(row0 + r) * 16 + (tid & 15)];
        float s = p.x, ss = p.y;
#pragma unroll
        for (int m = 1; m <= 8; m <<= 1) {   // stays inside 16-lane group
            s  += __shfl_xor(s, m);
            ss += __shfl_xor(ss, m);
        }
        if ((tid & 15) == 0) {
            float mu  = s * (1.0f / DOUT);
            float var = fmaxf(ss * (1.0f / DOUT) - mu * mu, 0.f);
            sh[r][0] = mu;
            sh[r][1] = rsqrtf(var + LN_EPS);
        }
    }
    __syncthreads();

    float4 g = ((const float4*)G)[e * 256 + tid];
    float4 b = ((const float4*)Bt)[e * 256 + tid];
#pragma unroll
    for (int r = 0; r < 8; r++) {
        float mu = sh[r][0], rs = sh[r][1];
        ushort4 hb = ((const ushort4*)Hb)[(size_t)(row0 + r) * 256 + tid];
        float4 y;
        y.x = (bf2f(hb.x) - mu) * rs * g.x + b.x;
        y.y = (bf2f(hb.y) - mu) * rs * g.y + b.y;
        y.z = (bf2f(hb.z) - mu) * rs * g.z + b.z;
        y.w = (bf2f(hb.w) - mu) * rs * g.w + b.w;
        ((float4*)Out)[(size_t)(row0 + r) * 256 + tid] = y;
    }
}

extern "C" void kernel_launch(void* const* d_in, const int* in_sizes, int n_in,
                              void* d_out, int out_size, void* d_ws, size_t ws_size,
                              hipStream_t stream) {
    const float* x  = (const float*)d_in[0];
    // d_in[1] = expert_frequency (int64) — equal loads, unused
    const float* W  = (const float*)d_in[2];
    const float* b  = (const float*)d_in[3];
    const float* g  = (const float*)d_in[4];
    const float* be = (const float*)d_in[5];
    float* out = (float*)d_out;

    const size_t WT_BYTES = (size_t)NEXP * DIN * DOUT * 2;   // 16 MB
    const size_t XB_BYTES = (size_t)T_TOK * DIN * 2;         // 16 MB
    const size_t P_BYTES  = (size_t)T_TOK * 16 * 8;          // 1 MB
    const size_t HB_BYTES = (size_t)T_TOK * DOUT * 2;        // 16 MB
    if (ws_size < WT_BYTES + XB_BYTES + P_BYTES + HB_BYTES) return;

    unsigned short* Wt = (unsigned short*)d_ws;
    unsigned short* Xb = (unsigned short*)((char*)d_ws + WT_BYTES);
    float2* P = (float2*)((char*)d_ws + WT_BYTES + XB_BYTES);
    unsigned short* Hb = (unsigned short*)((char*)d_ws + WT_BYTES + XB_BYTES + P_BYTES);

    prep_kernel<<<dim3(3072), dim3(256), 0, stream>>>(x, W, Xb, Wt);
    gemm7_kernel<<<dim3(256), dim3(512), 0, stream>>>(Xb, Wt, b, Hb, P);
    ln2_kernel<<<dim3(1024), dim3(256), 0, stream>>>(Hb, P, g, be, out);
}